// Round 5
// baseline (101.501 us; speedup 1.0000x reference)
//
#include <hip/hip_runtime.h>
#include <math.h>

// MultiWindowAttention B=4,L=2048,H=8,E=D=64 fp32; w = 32<<(h&3).
// Round 11: remove the barrier vmcnt-drain (T3/T4, m201 pattern).
//   R8/R9/R10 all bounced at ~28-31us: __syncthreads() emits
//   s_waitcnt vmcnt(0) before s_barrier, draining ALL prefetch every round
//   -> fetch duty-cycle ~50%, kernel = fetch + compute serialized.
//   Fix: main-loop barrier = { s_waitcnt lgkmcnt(0); s_barrier } only.
//   Compiler keeps counted vmcnt waits for the STAGE pack reads, so the
//   next tile's loads stay in flight across the barrier and under the next
//   compute phase. STAGE(s+1) moved BEFORE compute(s) (safe: buf[nxt] was
//   last read before the previous barrier) so ds_writes drain under compute.
//   Everything else = R10: 128-row i-tiles, 8 waves, band-skip fused
//   QK->exp->PV, 2-reg-set prefetch, XCD pinning, heavy/light pairing.

#define LL 2048
#define HH 8
#define EE 64
#define DD 64
#define RS (HH * EE)   // 512 floats between consecutive seq positions

typedef __attribute__((ext_vector_type(8))) short short8;
typedef __attribute__((ext_vector_type(4))) float floatx4;
typedef __attribute__((ext_vector_type(4))) _Float16 half4;
typedef __attribute__((ext_vector_type(2))) __fp16 fp16x2;   // cvt_pkrtz return type

static __device__ __forceinline__ unsigned f2bf(float f) {
    union { float f; unsigned u; } v; v.f = f;
    return (v.u + 0x7fff + ((v.u >> 16) & 1)) >> 16;   // RNE
}
static __device__ __forceinline__ unsigned pack2(float a, float b) {
    return f2bf(a) | (f2bf(b) << 16);
}
static __device__ __forceinline__ unsigned packh2(float a, float b) {
    union { fp16x2 h; unsigned u; } v;
    v.h = __builtin_amdgcn_cvt_pkrtz(a, b);
    return v.u;
}

// No-drain barrier: LDS writes visible, global loads stay in flight.
static __device__ __forceinline__ void barrier_nodrain() {
    asm volatile("s_waitcnt lgkmcnt(0)" ::: "memory");
    __builtin_amdgcn_s_barrier();
}

// LDS layout (shorts): K bufs [0, 8192) = 2 x 4096; V^T bufs [8192, 17408) = 2 x 4608 (ld=72)
#define K_BUF(cu)  (sAll + (cu) * 4096)
#define V_BUF(cu)  (sAll + 8192 + (cu) * 4608)

// ---- per-t4 fused compute: S^T += K.Q^T, mask, exp, P.V -> acc ----
static __device__ __forceinline__ void compute_tile(
    int j0, const short* __restrict__ kbase, const short* __restrict__ vbase,
    int w, int qb, int iq, int quad, int l15,
    short8 qf0, short8 qf1, floatx4* __restrict__ acc, float& lsum)
{
#pragma unroll
    for (int t4 = 0; t4 < 4; ++t4) {
        const int jb = j0 + t4 * 16;
        // wave-uniform band test for the 16q x 16j block
        if (jb > qb + 15 + w || jb + 15 < qb - w) continue;
        const bool needMask = ((jb + 15 - qb) > w) || ((qb + 15 - jb) > w);

        const short* kp = kbase + 1024 * t4 + 128 * quad + 8 * l15;
        short8 k0 = *(const short8*)kp;
        short8 k1 = *(const short8*)(kp + 512);
        floatx4 st = {};
        st = __builtin_amdgcn_mfma_f32_16x16x32_bf16(k0, qf0, st, 0, 0, 0);
        st = __builtin_amdgcn_mfma_f32_16x16x32_bf16(k1, qf1, st, 0, 0, 0);

        float pr[4];
        const int jq = jb + quad * 4;
#pragma unroll
        for (int r = 0; r < 4; ++r) {
            float x = st[r];
            if (needMask) {
                const int di = iq - (jq + r);
                x = (di <= w && di >= -w) ? x : -INFINITY;
            }
            pr[r] = __expf(x);
            lsum += pr[r];
        }
        half4 pf;
        {
            union { half4 v; unsigned u[2]; } pu;
            pu.u[0] = packh2(pr[0], pr[1]);
            pu.u[1] = packh2(pr[2], pr[3]);
            pf = pu.v;
        }
#pragma unroll
        for (int nt = 0; nt < 4; ++nt) {
            half4 vf = *(const half4*)(vbase + (nt * 16 + l15) * 72 + t4 * 16 + quad * 4);
            acc[nt] = __builtin_amdgcn_mfma_f32_16x16x16f16(pf, vf, acc[nt], 0, 0, 0);
        }
    }
}

// issue global loads for tile at row jn (K: 2x float4, V: 8 scalar rows)
#define ISSUE(jn, kf0_, kf1_, vv_)                                              \
    {                                                                           \
        const float4* src_ = (const float4*)(Kb + (size_t)((jn) + rowp) * RS + cp); \
        kf0_ = src_[0]; kf1_ = src_[1];                                         \
        _Pragma("unroll")                                                       \
        for (int rr_ = 0; rr_ < 8; ++rr_)                                       \
            vv_[rr_] = Vb[(size_t)((jn) + wv * 8 + rr_) * RS + lane];           \
    }

// pack registers -> LDS buffer bufIdx (compiler inserts counted vmcnt waits)
#define STAGE(bufIdx, kf0_, kf1_, vv_)                                          \
    {                                                                           \
        uint4 u0_ = { pack2(kf0_.x,kf0_.y), pack2(kf0_.z,kf0_.w),               \
                      pack2(kf1_.x,kf1_.y), pack2(kf1_.z,kf1_.w) };             \
        *(uint4*)&K_BUF(bufIdx)[kWoff] = u0_;                                   \
        uint4 w0_ = { packh2(vv_[0],vv_[1]), packh2(vv_[2],vv_[3]),             \
                      packh2(vv_[4],vv_[5]), packh2(vv_[6],vv_[7]) };           \
        *(uint4*)&V_BUF(bufIdx)[vWoff] = w0_;                                   \
    }

__global__ __launch_bounds__(512, 4) void mwa_r11(
    const float* __restrict__ Q,
    const float* __restrict__ K,
    const float* __restrict__ V,
    float* __restrict__ O)
{
    const int tid  = threadIdx.x;
    const int lane = tid & 63;
    const int wv   = tid >> 6;          // 0..7, wave owns q-rows wv*16..+15
    const int quad = lane >> 4;
    const int l15  = lane & 15;

    // ---- task decode (= R9/R10): heavy classes in gid<256; gid&7 fixed per (b,h) ----
    const int gid   = blockIdx.x;
    const int heavy = (gid >> 8) == 0;
    const int c     = gid & 255;
    const int it    = c >> 4;           // 0..15 (128-row i-tiles)
    const int rem   = c & 15;
    const int b     = rem >> 2;
    const int z     = rem & 3;
    const int hb    = z >> 1;
    const int p     = z & 1;
    const int h     = hb * 4 + (heavy ? (3 - p) : p);
    const int i0    = it << 7;
    const int w     = 32 << (h & 3);

    alignas(16) __shared__ short sAll[17408];   // 34816 B

    const float* Qb = Q + ((size_t)b * LL * HH + h) * EE;
    const float* Kb = K + ((size_t)b * LL * HH + h) * EE;
    const float* Vb = V + ((size_t)b * LL * HH + h) * DD;
    float*       Ob = O + ((size_t)b * LL * HH + h) * DD;

    // ---- stage Q (128 rows, bf16, ld=72, pre-scaled by 1/8); grab frags ----
    {
        const float sc = 0.125f;    // 2^-3: exact in bf16, folds softmax scale
        const int row = tid >> 2, cc = (tid & 3) << 4;
        const float4* src = (const float4*)(Qb + (size_t)(i0 + row) * RS + cc);
        float4 f0 = src[0], f1 = src[1], f2 = src[2], f3 = src[3];
        uint4 u0 = { pack2(sc*f0.x,sc*f0.y), pack2(sc*f0.z,sc*f0.w),
                     pack2(sc*f1.x,sc*f1.y), pack2(sc*f1.z,sc*f1.w) };
        uint4 u1 = { pack2(sc*f2.x,sc*f2.y), pack2(sc*f2.z,sc*f2.w),
                     pack2(sc*f3.x,sc*f3.y), pack2(sc*f3.z,sc*f3.w) };
        uint4* dst = (uint4*)&sAll[row * 72 + cc];   // 18432 B scratch
        dst[0] = u0; dst[1] = u1;
    }
    __syncthreads();
    short8 qf0, qf1;
    {
        const short* qp = &sAll[(wv * 16 + l15) * 72 + quad * 8];
        qf0 = *(const short8*)qp;
        qf1 = *(const short8*)(qp + 32);
    }
    __syncthreads();   // Q-frag reads done before K/V staging overwrites

    const int jt_lo = max(0, i0 - w) >> 6;
    const int jt_hi = min(LL - 1, i0 + 127 + w) >> 6;
    const int n     = jt_hi - jt_lo + 1;    // 3..10

    const int rowp  = tid >> 3, cp = (tid & 7) << 3;   // staging coords (64 rows x 8 floats)
    const int jtw   = rowp >> 4, l15w = rowp & 15, ks = cp >> 5, q0w = (cp >> 3) & 3;
    const int kWoff = (((jtw * 2 + ks) * 4 + q0w) * 16 + l15w) * 8;
    const int vWoff = lane * 72 + wv * 8;

    // ---- prologue: tile 0 -> buf0; issue tile 1 into set A ----
    float4 kA0, kA1; float vA[8];
    float4 kB0, kB1; float vB[8];
    ISSUE(jt_lo << 6, kA0, kA1, vA);
    STAGE(0, kA0, kA1, vA);
    if (n > 1) ISSUE((jt_lo + 1) << 6, kA0, kA1, vA);
    __syncthreads();   // full drain once at pipeline start: harmless

    floatx4 acc[4] = {};
    float lsum = 0.f;
    const int iq = i0 + wv * 16 + l15;   // this lane's query row (q = l15 in S^T)
    const int qb = i0 + wv * 16;         // wave's q-block base

    for (int s = 0; s < n; s += 2) {
        const int jt = jt_lo + s;
        // ---- even tile s: compute buf0; A holds s+1 -> stage buf1; issue s+2 -> B ----
        if (s + 2 < n) ISSUE((jt + 2) << 6, kB0, kB1, vB);
        if (s + 1 < n) STAGE(1, kA0, kA1, vA);
        compute_tile(jt << 6, K_BUF(0), V_BUF(0), w, qb, iq, quad, l15, qf0, qf1, acc, lsum);
        barrier_nodrain();

        if (s + 1 < n) {
            // ---- odd tile s+1: compute buf1; B holds s+2 -> stage buf0; issue s+3 -> A ----
            if (s + 3 < n) ISSUE((jt + 3) << 6, kA0, kA1, vA);
            if (s + 2 < n) STAGE(0, kB0, kB1, vB);
            compute_tile((jt + 1) << 6, K_BUF(1), V_BUF(1), w, qb, iq, quad, l15, qf0, qf1, acc, lsum);
            barrier_nodrain();
        }
    }

    // ---- epilogue: finish l, normalize, store (per-wave, no merge) ----
    lsum += __shfl_xor(lsum, 16, 64);
    lsum += __shfl_xor(lsum, 32, 64);      // lane (q = l15): row-sum over all j
    float rinv[4];
#pragma unroll
    for (int r = 0; r < 4; ++r) {
        const float lr = __shfl(lsum, quad * 4 + r, 64);
        rinv[r] = 1.0f / lr;
    }
#pragma unroll
    for (int nt = 0; nt < 4; ++nt) {
#pragma unroll
        for (int r = 0; r < 4; ++r) {
            Ob[(size_t)(i0 + wv * 16 + quad * 4 + r) * RS + nt * 16 + l15]
                = acc[nt][r] * rinv[r];
        }
    }
}

extern "C" void kernel_launch(void* const* d_in, const int* in_sizes, int n_in,
                              void* d_out, int out_size, void* d_ws, size_t ws_size,
                              hipStream_t stream)
{
    const float* Q = (const float*)d_in[0];
    const float* K = (const float*)d_in[1];
    const float* V = (const float*)d_in[2];
    float* O = (float*)d_out;

    dim3 grid(512), block(512);
    hipLaunchKernelGGL(mwa_r11, grid, block, 0, stream, Q, K, V, O);
}